// Round 6
// baseline (1654.216 us; speedup 1.0000x reference)
//
#include <hip/hip_runtime.h>
#include <cstdint>
#include <cstddef>

// LaminarV1V2Network: B=1024, T=512, N=36, H=128, D_in=74, K=202.
// R10 = R9 with P5+P6 merged -> 3 barriers/step:
//  P1: zr GEMM (w0-7) || l4-finalize+stim (auxA<144) || l23dot ([144,288))
//      || somdot ([288,432))   [all on w8-15]
//  P3: h GEMM (w8-15) || PV (w0) || l4part-dot (w1-3)
//  P56: heads GEMM + IN-REGISTER softmax + pointwise + out, ALL on wave 0
//       (12 MFMA: 3 col-tiles x 4 slabs; q-group g handles batch
//       (g&1)*2|(g>>1); DPP-16 reductions; head frags staged in LDS,
//       re-read per step -> no persistent-register cost) || cue (w1-2)
// l4f(t) now computes l4(t) at START of step t (parity-buffered l4s[2]).
// Structure otherwise R9: 256x1024 (16 waves), RPB=4, 8-row A packing
// (row=batch*2+part, in-lane hi/lo combine, no shfl), KP=232, HSTR=136.

#define NN   36
#define HH   128
#define DIN  74
#define KT   202
#define KP   232      // row = 116 words == 20 mod 32 -> 8-row map bank-uniform
#define TT   512
#define RPB  4
#define NPAD 40
#define HSTR 136      // hb row stride (shorts): 68 words == 4 mod 32 -> bank-uniform
#define S2   6        // second-dim stride for hS/zgS

typedef short bf16x8 __attribute__((ext_vector_type(8)));
typedef float f32x4  __attribute__((ext_vector_type(4)));

#define MFMA(a,b,c) __builtin_amdgcn_mfma_f32_16x16x32_bf16((a),(b),(c),0,0,0)
// Barrier that orders LDS only: global loads/stores float across it.
#define BAR() asm volatile("s_waitcnt lgkmcnt(0)\n\ts_barrier" ::: "memory")

__device__ __forceinline__ float fastrcp(float x) { return __builtin_amdgcn_rcpf(x); }
__device__ __forceinline__ float sigmf(float x) { return fastrcp(1.0f + __expf(-x)); }
__device__ __forceinline__ float tanhf_fast(float x) {
    return 1.0f - 2.0f * fastrcp(1.0f + __expf(2.0f * x));
}

__device__ __forceinline__ short f2bf(float v) {
    union { float f; unsigned u; } x; x.f = v;
    unsigned r = (x.u + 0x7fffu + ((x.u >> 16) & 1u)) >> 16;   // RNE
    return (short)r;
}
__device__ __forceinline__ float bf2f(short s) {
    union { unsigned u; float f; } y; y.u = ((unsigned)(unsigned short)s) << 16;
    return y.f;
}

// v_cvt_pk_bf16_f32: dst[15:0]=bf16(a), dst[31:16]=bf16(b), RNE (same as f2bf).
__device__ __forceinline__ unsigned cvtpk(float a, float b) {
    unsigned r;
    asm("v_cvt_pk_bf16_f32 %0, %1, %2" : "=v"(r) : "v"(a), "v"(b));
    return r;
}
__device__ __forceinline__ float lo16f(unsigned p) { return __uint_as_float(p << 16); }
__device__ __forceinline__ float hi16f(unsigned p) { return __uint_as_float(p & 0xffff0000u); }

// 16-lane butterfly reduction at VALU speed via DPP.
#define DPP_STEP_MAX(x, ctrl) \
    x = fmaxf(x, __int_as_float(__builtin_amdgcn_update_dpp(0, __float_as_int(x), (ctrl), 0xF, 0xF, true)))
#define DPP_STEP_SUM(x, ctrl) \
    x = x + __int_as_float(__builtin_amdgcn_update_dpp(0, __float_as_int(x), (ctrl), 0xF, 0xF, true))

__device__ __forceinline__ float red16_max(float x) {
    DPP_STEP_MAX(x, 0xB1);   // quad_perm xor1
    DPP_STEP_MAX(x, 0x4E);   // quad_perm xor2
    DPP_STEP_MAX(x, 0x141);  // row_half_mirror
    DPP_STEP_MAX(x, 0x140);  // row_mirror
    return x;
}
__device__ __forceinline__ float red16_sum(float x) {
    DPP_STEP_SUM(x, 0xB1);
    DPP_STEP_SUM(x, 0x4E);
    DPP_STEP_SUM(x, 0x141);
    DPP_STEP_SUM(x, 0x140);
    return x;
}

// ---- fragment layout in ws (shorts) ---- (unchanged from R5)
#define HEADBASE 86016
#define FRAG_TOTAL 92160

extern "C" __global__ void __launch_bounds__(256)
init_frags(const float* __restrict__ Wz, const float* __restrict__ Wr,
           const float* __restrict__ Wh, const float* __restrict__ Wq,
           const float* __restrict__ Wp, short* __restrict__ frag)
{
    int idx = blockIdx.x * 256 + threadIdx.x;
    if (idx >= FRAG_TOTAL) return;
    float v;
    if (idx < HEADBASE) {
        int T = idx / 3584; int rem = idx - T * 3584;
        int s = rem >> 9;   int e = rem & 511;
        int l = e >> 3, j = e & 7;
        int k = s * 32 + ((l >> 4) << 3) + j;
        int n = ((T & 7) << 4) + (l & 15);
        const float* W = (T < 8) ? Wz : (T < 16) ? Wr : Wh;
        v = (k < KT) ? W[k * HH + n] : 0.f;
    } else {
        int r2 = idx - HEADBASE;
        int ts = r2 >> 9; int e = r2 & 511;
        int t = ts >> 2, s = ts & 3;
        int l = e >> 3, j = e & 7;
        int k = s * 32 + ((l >> 4) << 3) + j;     // < 128
        int c = (t << 4) + (l & 15);
        v = (c < NN) ? Wq[k * NN + c] : (c == NN ? Wp[k] : 0.f);
    }
    frag[idx] = f2bf(v);
}

extern "C" __global__ void __launch_bounds__(1024, 4)
laminar_kernel(const float* __restrict__ packed,
               const float* __restrict__ Wl4,
               const float* __restrict__ Wl23,
               const float* __restrict__ Wsom,
               const float* __restrict__ bz,
               const float* __restrict__ br,
               const float* __restrict__ bh,
               const float* __restrict__ bq,
               const float* __restrict__ bp,
               const short* __restrict__ frag,
               float* __restrict__ out)
{
    const int tid  = threadIdx.x;
    const int r0   = blockIdx.x * RPB;
    const int lane = tid & 63;
    const int w    = tid >> 6;           // 0..15
    const int m    = lane & 15;
    const int q    = lane >> 4;
    // A rows 0..7 = (batch,part): row = batch*2+part; rows 8..15 duplicate.
    // In-lane hi/lo combine: batch b0i = acc[0]+acc[1], b1i = acc[2]+acc[3].
    const int arow = m & 7;
    const int ab   = arow >> 1;          // batch row 0..3
    const int ap   = arow & 1;           // 0: hi part, 1: lo part
    const int b0i  = (q & 1) << 1;       // epilogue batch (lanes<32)
    const int b1i  = b0i + 1;

    __shared__ __align__(16) short xa[2][RPB][KP];   // [part][batch][k]: z/r A
    __shared__ __align__(16) short xb[2][RPB][KP];   // hh A (cols 64+ used)
    __shared__ __align__(16) short hbS[2][RPB][HSTR]; // head A: h_new
    __shared__ __align__(16) short HdL[6144];        // head frags (12 x 512)
    __shared__ float hS[HH][S2];      // h state, [feature][row]
    __shared__ float zgS[HH][S2];     // z gate PRE-ACT (+bias); sigmoid in P3
    // ring weights chunk-major: [(c*36+i)*4 + d] = W[i][4c+d]
    __shared__ __align__(16) float W4l4[1296], W4l23[1296], W4som[1296];
    __shared__ __align__(16) float l4s[2][RPB][NPAD];   // parity: l4(t) in l4s[t&1]
    __shared__ __align__(16) float l23s[RPB][NPAD];
    __shared__ __align__(16) float soms[RPB][NPAD], adL[RPB][NPAD];
    __shared__ __align__(16) float l4part[RPB][NPAD];   // stim+Wl4*l4-adapt pipeline
    __shared__ __align__(16) float l23dotS[RPB][NPAD];  // Wl23*l23(t-1)
    __shared__ __align__(16) float somdotS[RPB][NPAD];  // Wsom*som(t-1)
    __shared__ float bzL[HH], brL[HH], bhL[HH], bqL[48];
    __shared__ float pvL[RPB];
    __shared__ float bpS;

    // ---- one-time init ----
    for (int i = tid; i < HH; i += 1024) { bzL[i] = bz[i]; brL[i] = br[i]; bhL[i] = bh[i]; }
    for (int i = tid; i < 48; i += 1024) bqL[i] = (i < NN) ? bq[i] : 0.f;
    if (tid == 0) bpS = bp[0];
    for (int idx = tid; idx < 324; idx += 1024) {
        const int c = idx / NN, i = idx - c * NN;
        const int o = idx * 4;
        #pragma unroll
        for (int d = 0; d < 4; ++d) {
            W4l4[o + d]  = Wl4[i * NN + 4 * c + d];
            W4l23[o + d] = Wl23[i * NN + 4 * c + d];
            W4som[o + d] = Wsom[i * NN + 4 * c + d];
        }
    }
    for (int i = tid; i < 6144; i += 1024) HdL[i] = frag[HEADBASE + i];
    { short* p = (short*)xa;  for (int i = tid; i < 2*RPB*KP;   i += 1024) p[i] = 0; }
    { short* p = (short*)xb;  for (int i = tid; i < 2*RPB*KP;   i += 1024) p[i] = 0; }
    { short* p = (short*)hbS; for (int i = tid; i < 2*RPB*HSTR; i += 1024) p[i] = 0; }
    { float* p = (float*)hS;  for (int i = tid; i < HH*S2;      i += 1024) p[i] = 0.f; }
    { float* p = (float*)l4s; for (int i = tid; i < 2*RPB*NPAD; i += 1024) p[i] = 0.f; }
    { float* p = (float*)l23s; for (int i = tid; i < RPB*NPAD;  i += 1024) {
        p[i] = 0.f; ((float*)soms)[i] = 0.f; ((float*)adL)[i] = 0.f;
        ((float*)l23dotS)[i] = 0.f; ((float*)somdotS)[i] = 0.f; } }
    if (tid < RPB) pvL[tid] = 0.f;

    // ---- persistent weight fragments (split across wave groups) ----
    bf16x8 FA[7], FB[7];
    if (w < 8) {
        const short* a0 = frag + (w * 7) * 512 + lane * 8;          // Wz tile w
        const short* b0 = frag + ((8 + w) * 7) * 512 + lane * 8;    // Wr tile w
        #pragma unroll
        for (int s = 0; s < 7; ++s) {
            FA[s] = *(const bf16x8*)(a0 + s * 512);
            FB[s] = *(const bf16x8*)(b0 + s * 512);
        }
    } else {
        const short* a0 = frag + ((16 + (w - 8)) * 7) * 512 + lane * 8; // Wh tile
        #pragma unroll
        for (int s = 0; s < 7; ++s) { FA[s] = *(const bf16x8*)(a0 + s * 512); FB[s] = FA[s]; }
    }

    // ---- aux role assignment ----
    // P1 aux pool on w8-15, flat id:
    const int  auxA = (w - 8) * 64 + lane;
    const bool isL4f  = (w >= 8) && (auxA < 144);
    const bool isDotA = (w >= 8) && (auxA >= 144) && (auxA < 288);   // l23dot
    const bool isDotC = (w >= 8) && (auxA >= 288) && (auxA < 432);   // somdot
    const int  vB = isL4f ? auxA : 0;
    const int  lr = vB / 36, li = vB - lr * 36;
    const int  vA = isDotA ? (auxA - 144) : 0;
    const int  drA = vA / 36, diA = vA - drA * 36;
    const float* dAW = W4l23 + diA * 4;
    const int  vC = isDotC ? (auxA - 288) : 0;
    const int  crC = vC / 36, ciC = vC - crC * 36;
    const float* dCW = W4som + ciC * 4;
    // P3: l4part dot-add on w1-3
    const int  auxB = (w - 1) * 64 + lane;
    const bool isL4p = (w >= 1 && w < 4) && (auxB < 144);
    const int  vD = isL4p ? auxB : 0;
    const int  prD = vD / 36, piD = vD - prD * 36;
    const float* pW = W4l4 + piD * 4;
    // P56: cue/task staging on w1-2 (4 rows x 19 thr x 2 cols)
    const int  auxC = (w - 1) * 64 + lane;
    const bool isCue = (w >= 1 && w < 3) && (auxC < 76);
    const int  evE = isCue ? auxC : 0;
    const int  ctr = evE / 19;
    const int  ctc = 36 + 2 * (evE - ctr * 19);   // 36..72 even

    __syncthreads();   // zero-init complete before prologue overwrites

    // ---- prologue ----
    // l4part(0) = stim(0); stimreg = stim(1); cue(0) staged, cue(1) prefetched.
    // All state (l4s both parities, l23s, soms, adL, pvL) zero = state(-1).
    float ctv0 = 0.f, ctv1 = 0.f, stimreg = 0.f;
    if (tid < RPB * NN) {
        const int r = tid / NN, i = tid - (tid / NN) * NN;
        l4part[r][i] = packed[((size_t)(r0 + r) * TT + 0) * DIN + i];
    }
    if (isL4f) stimreg = packed[((size_t)(r0 + lr) * TT + 1) * DIN + li];
    if (isCue) {
        const size_t base0 = ((size_t)(r0 + ctr) * TT + 0) * DIN;
        #pragma unroll
        for (int d = 0; d < 2; ++d) {
            const float v = packed[base0 + ctc + d];
            const short hi = f2bf(v), lo = f2bf(v - bf2f(hi));
            xa[0][ctr][ctc + d] = hi; xa[1][ctr][ctc + d] = lo;
            if (ctc + d >= 64) { xb[0][ctr][ctc + d] = hi; xb[1][ctr][ctc + d] = lo; }
        }
        const size_t base1 = ((size_t)(r0 + ctr) * TT + 1) * DIN;
        ctv0 = packed[base1 + ctc]; ctv1 = packed[base1 + ctc + 1];
    }
    __syncthreads();

    for (int t = 0; t < TT; ++t) {
        float (*l4cur)[NPAD]  = l4s[t & 1];         // l4(t), written by l4f below
        float (*l4prev)[NPAD] = l4s[(t + 1) & 1];   // l4(t-1)

        // ---- P1: zr GEMM (w0-7) || l4f (auxA<144) || l23dot || somdot ----
        if (w < 8) {
            const short* xaRow = &xa[ap][ab][0];
            bf16x8 Ax[7];
            #pragma unroll
            for (int s = 0; s < 7; ++s)
                Ax[s] = *(const bf16x8*)&xaRow[s * 32 + q * 8];
            f32x4 az = {0.f,0.f,0.f,0.f}, ar = {0.f,0.f,0.f,0.f};
            #pragma unroll
            for (int s = 0; s < 7; ++s) {
                az = MFMA(Ax[s], FA[s], az);
                ar = MFMA(Ax[s], FB[s], ar);
            }
            if (lane < 32) {
                const int f = w * 16 + m;
                const float z0 = az[0] + az[1], z1 = az[2] + az[3];
                const float r0v = ar[0] + ar[1], r1v = ar[2] + ar[3];
                zgS[f][b0i] = z0 + bzL[f];         // pre-act; sigmoid in P3
                zgS[f][b1i] = z1 + bzL[f];
                const float ra = sigmf(r0v + brL[f]) * hS[f][b0i];
                const float rb = sigmf(r1v + brL[f]) * hS[f][b1i];
                const unsigned ph = cvtpk(ra, rb);
                const unsigned pl = cvtpk(ra - lo16f(ph), rb - hi16f(ph));
                xb[0][b0i][DIN + f] = (short)ph;         xb[1][b0i][DIN + f] = (short)pl;
                xb[0][b1i][DIN + f] = (short)(ph >> 16); xb[1][b1i][DIN + f] = (short)(pl >> 16);
            }
        } else if (isL4f) {
            // l4(t) = 0.9*l4(t-1) + 0.1*relu(l4part(t) - pv(t-1))
            const float nl4 = 0.9f * l4prev[lr][li]
                            + 0.1f * fmaxf(l4part[lr][li] - pvL[lr], 0.f);
            l4cur[lr][li] = nl4;
            const float ad = 0.98f * adL[lr][li] + 0.01f * nl4;
            adL[lr][li] = ad;
            l4part[lr][li] = stimreg - ad;     // base for t+1: stim(t+1)-adapt(t)
            const int tn = (t + 2 < TT) ? t + 2 : TT - 1;
            stimreg = packed[((size_t)(r0 + lr) * TT + tn) * DIN + li];
        } else if (isDotA) {                   // l23dot(t) from l23(t-1)
            float acc = 0.f;
            #pragma unroll
            for (int c = 0; c < 9; ++c) {
                const float4 wv = *(const float4*)&dAW[c * 144];
                const float4 sv = *(const float4*)&l23s[drA][4 * c];
                acc += sv.x*wv.x + sv.y*wv.y + sv.z*wv.z + sv.w*wv.w;
            }
            l23dotS[drA][diA] = acc;
        } else if (isDotC) {                   // somdot(t) from som(t-1)
            float acc = 0.f;
            #pragma unroll
            for (int c = 0; c < 9; ++c) {
                const float4 wv = *(const float4*)&dCW[c * 144];
                const float4 sv = *(const float4*)&soms[crC][4 * c];
                acc += sv.x*wv.x + sv.y*wv.y + sv.z*wv.z + sv.w*wv.w;
            }
            somdotS[crC][ciC] = acc;
        }
        BAR();

        // ---- P3: h GEMM (w8-15) || PV (w0) || l4part-dot (w1-3) ----
        if (w >= 8) {
            const short* xaRow = &xa[ap][ab][0];
            const short* xbRow = &xb[ap][ab][0];
            bf16x8 Op[7];
            Op[0] = *(const bf16x8*)&xaRow[q * 8];
            Op[1] = *(const bf16x8*)&xaRow[32 + q * 8];
            #pragma unroll
            for (int s = 2; s < 7; ++s)
                Op[s] = *(const bf16x8*)&xbRow[s * 32 + q * 8];
            f32x4 a = {0.f,0.f,0.f,0.f}, b = {0.f,0.f,0.f,0.f};
            a = MFMA(Op[0], FA[0], a);
            b = MFMA(Op[1], FA[1], b);
            a = MFMA(Op[2], FA[2], a);
            b = MFMA(Op[3], FA[3], b);
            a = MFMA(Op[4], FA[4], a);
            b = MFMA(Op[5], FA[5], b);
            a = MFMA(Op[6], FA[6], a);
            a = a + b;
            if (lane < 32) {
                const int f = (w - 8) * 16 + m;
                const float s0 = a[0] + a[1], s1 = a[2] + a[3];
                const float hh0 = tanhf_fast(s0 + bhL[f]);
                const float hh1 = tanhf_fast(s1 + bhL[f]);
                const float zg0 = sigmf(zgS[f][b0i]);
                const float zg1 = sigmf(zgS[f][b1i]);
                const float hn0 = (1.0f - zg0) * hS[f][b0i] + zg0 * hh0;
                const float hn1 = (1.0f - zg1) * hS[f][b1i] + zg1 * hh1;
                hS[f][b0i] = hn0; hS[f][b1i] = hn1;
                const unsigned ph = cvtpk(hn0, hn1);
                const unsigned pl = cvtpk(hn0 - lo16f(ph), hn1 - hi16f(ph));
                hbS[0][b0i][f] = (short)ph;         hbS[1][b0i][f] = (short)pl;
                hbS[0][b1i][f] = (short)(ph >> 16); hbS[1][b1i][f] = (short)(pl >> 16);
                xa[0][b0i][DIN + f] = (short)ph;         xa[1][b0i][DIN + f] = (short)pl;
                xa[0][b1i][DIN + f] = (short)(ph >> 16); xa[1][b1i][DIN + f] = (short)(pl >> 16);
            }
        } else if (w == 0) {                   // PV: l4(t) + l23(t-1), DPP reduce
            const int row = q;                 // 0..3
            float s = l4cur[row][m] + l23s[row][m] + l4cur[row][m + 16] + l23s[row][m + 16];
            if (m < 4) s += l4cur[row][m + 32] + l23s[row][m + 32];
            s = red16_sum(s);
            if (m == 0) pvL[row] = 0.9f * pvL[row] + 0.1f * fmaxf(s * (1.0f / 36.0f), 0.f);
        } else if (isL4p) {                    // l4part(t+1) += Wl4*l4(t)
            const float* pS = &l4cur[prD][0];
            float acc = l4part[prD][piD];
            #pragma unroll
            for (int c = 0; c < 9; ++c) {
                const float4 wv = *(const float4*)&pW[c * 144];
                const float4 sv = *(const float4*)&pS[4 * c];
                acc += sv.x*wv.x + sv.y*wv.y + sv.z*wv.z + sv.w*wv.w;
            }
            l4part[prD][piD] = acc;
        }
        BAR();

        // ---- P56: heads + in-reg softmax + pointwise (w0) || cue (w1-2) ----
        if (w == 0) {
            const short* hbRow = &hbS[ap][ab][0];
            bf16x8 Hk[4];
            #pragma unroll
            for (int s = 0; s < 4; ++s)
                Hk[s] = *(const bf16x8*)&hbRow[s * 32 + q * 8];
            f32x4 a0 = {0.f,0.f,0.f,0.f}, a1 = {0.f,0.f,0.f,0.f}, a2 = {0.f,0.f,0.f,0.f};
            bf16x8 HdA[4], HdB[4];
            #pragma unroll
            for (int s = 0; s < 4; ++s) HdA[s] = *(const bf16x8*)&HdL[s * 512 + lane * 8];
            #pragma unroll
            for (int s = 0; s < 4; ++s) a0 = MFMA(Hk[s], HdA[s], a0);
            #pragma unroll
            for (int s = 0; s < 4; ++s) HdB[s] = *(const bf16x8*)&HdL[(4 + s) * 512 + lane * 8];
            #pragma unroll
            for (int s = 0; s < 4; ++s) a1 = MFMA(Hk[s], HdB[s], a1);
            #pragma unroll
            for (int s = 0; s < 4; ++s) HdA[s] = *(const bf16x8*)&HdL[(8 + s) * 512 + lane * 8];
            #pragma unroll
            for (int s = 0; s < 4; ++s) a2 = MFMA(Hk[s], HdA[s], a2);
            // q-group g handles batch ((g&1)<<1)|(g>>1); rows-sum select by g>>1
            const int  hsel = q >> 1;
            const int  bat  = ((q & 1) << 1) | hsel;
            const float v0  = (hsel ? (a0[2] + a0[3]) : (a0[0] + a0[1])) + bqL[m];
            const float v1  = (hsel ? (a1[2] + a1[3]) : (a1[0] + a1[1])) + bqL[m + 16];
            const float v2r =  hsel ? (a2[2] + a2[3]) : (a2[0] + a2[1]);
            const float v2  = (m < 4) ? (v2r + bqL[m + 32]) : -1e30f;
            const float pi  = sigmf(__shfl(v2r, (lane & 48) | 4) + bpS);  // col 36
            const float mx = red16_max(fmaxf(fmaxf(v0, v1), v2));
            const float e0 = __expf(v0 - mx);
            const float e1 = __expf(v1 - mx);
            const float e2 = (m < 4) ? __expf(v2 - mx) : 0.f;
            const float ss = red16_sum(e0 + e1 + e2);
            const float sc = fastrcp(ss) * pi;
            const float pv = pvL[bat];
            const size_t outb = ((size_t)(r0 + bat) * TT + t) * NN;
            float ln01[2];
            #pragma unroll
            for (int t2 = 0; t2 < 2; ++t2) {
                const int i = m + 16 * t2;
                const float dt = (t2 ? e1 : e0) * sc;
                const float sn = 0.9f * soms[bat][i]
                               + 0.1f * fmaxf(dt + somdotS[bat][i], 0.f);
                soms[bat][i] = sn;
                const float acc2 = (l4cur[bat][i] - dt) * (1.0f + 0.5f * dt)
                                 + l23dotS[bat][i] - 0.8f * sn - pv;
                const float ln = 0.9f * l23s[bat][i] + 0.1f * fmaxf(acc2, 0.f);
                l23s[bat][i] = ln;
                out[outb + i] = ln;
                ln01[t2] = ln;
            }
            const unsigned ph = cvtpk(ln01[0], ln01[1]);
            const unsigned pl = cvtpk(ln01[0] - lo16f(ph), ln01[1] - hi16f(ph));
            xa[0][bat][m]      = (short)ph;         xa[1][bat][m]      = (short)pl;
            xa[0][bat][m + 16] = (short)(ph >> 16); xa[1][bat][m + 16] = (short)(pl >> 16);
            if (m < 4) {
                const int i = m + 32;
                const float dt = e2 * sc;
                const float sn = 0.9f * soms[bat][i]
                               + 0.1f * fmaxf(dt + somdotS[bat][i], 0.f);
                soms[bat][i] = sn;
                const float acc2 = (l4cur[bat][i] - dt) * (1.0f + 0.5f * dt)
                                 + l23dotS[bat][i] - 0.8f * sn - pv;
                const float ln = 0.9f * l23s[bat][i] + 0.1f * fmaxf(acc2, 0.f);
                l23s[bat][i] = ln;
                out[outb + i] = ln;
                const short hi2 = f2bf(ln);
                xa[0][bat][i] = hi2; xa[1][bat][i] = f2bf(ln - bf2f(hi2));
            }
        } else if (isCue) {                    // cue/task(t+1) -> LDS; prefetch t+2
            const unsigned ph = cvtpk(ctv0, ctv1);
            const unsigned pl = cvtpk(ctv0 - lo16f(ph), ctv1 - hi16f(ph));
            xa[0][ctr][ctc]     = (short)ph;         xa[1][ctr][ctc]     = (short)pl;
            xa[0][ctr][ctc + 1] = (short)(ph >> 16); xa[1][ctr][ctc + 1] = (short)(pl >> 16);
            if (ctc >= 64) {   // ctc even, so ctc>=64 <=> ctc+1>=64
                xb[0][ctr][ctc]     = (short)ph;         xb[1][ctr][ctc]     = (short)pl;
                xb[0][ctr][ctc + 1] = (short)(ph >> 16); xb[1][ctr][ctc + 1] = (short)(pl >> 16);
            }
            const int tn = (t + 2 < TT) ? t + 2 : TT - 1;
            const size_t base = ((size_t)(r0 + ctr) * TT + tn) * DIN;
            ctv0 = packed[base + ctc]; ctv1 = packed[base + ctc + 1];
        }
        BAR();
    }
}

extern "C" void kernel_launch(void* const* d_in, const int* in_sizes, int n_in,
                              void* d_out, int out_size, void* d_ws, size_t ws_size,
                              hipStream_t stream) {
    (void)in_sizes; (void)n_in; (void)out_size; (void)ws_size;
    const float* packed = (const float*)d_in[0];
    const float* Wl4    = (const float*)d_in[1];
    const float* Wl23   = (const float*)d_in[2];
    const float* Wsom   = (const float*)d_in[3];
    const float* Wz     = (const float*)d_in[4];
    const float* Wr     = (const float*)d_in[5];
    const float* Wh     = (const float*)d_in[6];
    const float* bz     = (const float*)d_in[7];
    const float* br     = (const float*)d_in[8];
    const float* bh     = (const float*)d_in[9];
    const float* Wq     = (const float*)d_in[10];
    const float* bq     = (const float*)d_in[11];
    const float* Wp     = (const float*)d_in[12];
    const float* bp     = (const float*)d_in[13];
    float* out  = (float*)d_out;
    short* frag = (short*)d_ws;   // needs 184320 B

    init_frags<<<(FRAG_TOTAL + 255) / 256, 256, 0, stream>>>(Wz, Wr, Wh, Wq, Wp, frag);
    laminar_kernel<<<256, 1024, 0, stream>>>(packed, Wl4, Wl23, Wsom,
                                             bz, br, bh, bq, bp, frag, out);
}